// Round 1
// baseline (334.620 us; speedup 1.0000x reference)
//
#include <hip/hip_runtime.h>
#include <hip/hip_bf16.h>
#include <math.h>

// Problem: out = GELU_exact(x @ W.T + b)
//   x: [8192, 512] f32, W: [512, 512] f32 (row = out-feature), b: [512] f32
//   adj (d_in[1]) and a (d_in[4]) are dead code in the reference.
// Strategy: cast x,W -> bf16 in ws, then m97-style 128x128 MFMA GEMM
// (16x16x32 bf16, global_load_lds width 16), fused bias+GELU epilogue.

#define NROWS 8192
#define KD    512
#define NOUT  512

using short8  = __attribute__((ext_vector_type(8))) short;
using floatx4 = __attribute__((ext_vector_type(4))) float;

#define GLOBAL_AS(p) ((const __attribute__((address_space(1))) void*)(p))
#define LDS_AS(p)    ((__attribute__((address_space(3))) void*)(p))

__device__ __forceinline__ unsigned short f32_to_bf16(float f) {
  unsigned int u = __float_as_uint(f);
  u += 0x7FFFu + ((u >> 16) & 1u);   // round-to-nearest-even
  return (unsigned short)(u >> 16);
}

// ---- kernel 1: cast x and W to bf16 into workspace -------------------------
// total 16B-output chunks: (8192*512 + 512*512)/8 = 557056 = 2176 blocks * 256
__global__ __launch_bounds__(256) void cast_bf16_kernel(
    const float* __restrict__ x, const float* __restrict__ W,
    unsigned short* __restrict__ xb, unsigned short* __restrict__ wb) {
  const int i  = blockIdx.x * 256 + threadIdx.x;
  const int XV = (NROWS * KD) / 8;  // 524288
  const float* src;
  unsigned short* dst;
  int idx;
  if (i < XV) { src = x; dst = xb; idx = i; }
  else        { src = W; dst = wb; idx = i - XV; }
  floatx4 v0 = ((const floatx4*)src)[idx * 2 + 0];
  floatx4 v1 = ((const floatx4*)src)[idx * 2 + 1];
  short8 o;
  o[0] = (short)f32_to_bf16(v0[0]);
  o[1] = (short)f32_to_bf16(v0[1]);
  o[2] = (short)f32_to_bf16(v0[2]);
  o[3] = (short)f32_to_bf16(v0[3]);
  o[4] = (short)f32_to_bf16(v1[0]);
  o[5] = (short)f32_to_bf16(v1[1]);
  o[6] = (short)f32_to_bf16(v1[2]);
  o[7] = (short)f32_to_bf16(v1[3]);
  *(short8*)(dst + (size_t)idx * 8) = o;
}

// ---- kernel 2: bf16 MFMA GEMM + bias + exact GELU --------------------------
// C[m][n] = sum_k A[m][k]*W[n][k]  (gemm_bt: both operands row-major in K)
// Tile: BM=BN=128, BK=32. Block: 256 threads = 4 waves (2x2), wave = 64x64.
__global__ __launch_bounds__(256) void gemm_bias_gelu(
    const unsigned short* __restrict__ A,   // [8192][512] bf16
    const unsigned short* __restrict__ B,   // [512][512]  bf16 (W)
    const float* __restrict__ bias,         // [512]
    float* __restrict__ C) {                // [8192][512] f32
  __shared__ __align__(16) unsigned short lA[128 * 32];  // 8 KB
  __shared__ __align__(16) unsigned short lB[128 * 32];  // 8 KB

  const int tid  = threadIdx.x;
  const int bn   = blockIdx.x;   // 0..3
  const int bm   = blockIdx.y;   // 0..63
  const int wave = tid >> 6;
  const int lane = tid & 63;
  const int quad = lane >> 4;
  const int l16  = lane & 15;
  const int wm   = (wave >> 1) * 64;   // wave row offset in tile
  const int wn   = (wave & 1) * 64;    // wave col offset in tile

  // Staging: tile is 128 rows x 32 bf16 (64 B/row) = 512 chunks of 16 B.
  // chunk c = i*256 + tid  (i=0,1): row = c>>2, elem col = (c&3)*8.
  // LDS dest must be wave-uniform base + lane*16 (HW scatter rule):
  // elem offset = c*8 = i*2048 + wave*512 + lane*8.
  const int r0 = tid >> 2;             // rows 0..63   (i=0)
  const int e0 = (tid & 3) * 8;
  unsigned short* lA0 = lA + wave * 512;
  unsigned short* lA1 = lA + 2048 + wave * 512;
  unsigned short* lB0 = lB + wave * 512;
  unsigned short* lB1 = lB + 2048 + wave * 512;

  const unsigned short* Ab = A + (size_t)bm * 128 * KD;
  const unsigned short* Bb = B + (size_t)bn * 128 * KD;

  floatx4 acc[4][4] = {};

  for (int kt = 0; kt < KD / 32; ++kt) {
    const int k0 = kt * 32;
    const unsigned short* ga0 = Ab + (size_t)r0 * KD + k0 + e0;
    const unsigned short* ga1 = ga0 + (size_t)64 * KD;   // rows 64..127 (i=1)
    const unsigned short* gb0 = Bb + (size_t)r0 * KD + k0 + e0;
    const unsigned short* gb1 = gb0 + (size_t)64 * KD;

    __builtin_amdgcn_global_load_lds(GLOBAL_AS(ga0), LDS_AS(lA0), 16, 0, 0);
    __builtin_amdgcn_global_load_lds(GLOBAL_AS(ga1), LDS_AS(lA1), 16, 0, 0);
    __builtin_amdgcn_global_load_lds(GLOBAL_AS(gb0), LDS_AS(lB0), 16, 0, 0);
    __builtin_amdgcn_global_load_lds(GLOBAL_AS(gb1), LDS_AS(lB1), 16, 0, 0);
    __syncthreads();   // compiler drains vmcnt(0) before s_barrier

    // Fragments: lane holds op[row = l16][k = quad*8 .. quad*8+7]
    short8 af[4], bfr[4];
#pragma unroll
    for (int t = 0; t < 4; ++t) {
      af[t]  = *(const short8*)(lA + (wm + t * 16 + l16) * 32 + quad * 8);
      bfr[t] = *(const short8*)(lB + (wn + t * 16 + l16) * 32 + quad * 8);
    }
#pragma unroll
    for (int i = 0; i < 4; ++i)
#pragma unroll
      for (int j = 0; j < 4; ++j)
        acc[i][j] =
            __builtin_amdgcn_mfma_f32_16x16x32_bf16(af[i], bfr[j], acc[i][j], 0, 0, 0);
    __syncthreads();   // protect LDS before next stage overwrites
  }

  // Epilogue. C/D layout (verified m89/m91): col = lane&15, row = quad*4 + reg.
  const int row0 = bm * 128 + wm;
  const int col0 = bn * 128 + wn;
#pragma unroll
  for (int i = 0; i < 4; ++i) {
#pragma unroll
    for (int j = 0; j < 4; ++j) {
      const int col = col0 + j * 16 + l16;
      const float bv = bias[col];
#pragma unroll
      for (int r = 0; r < 4; ++r) {
        const int row = row0 + i * 16 + quad * 4 + r;
        float v = acc[i][j][r] + bv;
        float g = 0.5f * v * (1.0f + erff(v * 0.70710678118654752f));
        C[(size_t)row * NOUT + col] = g;
      }
    }
  }
}

extern "C" void kernel_launch(void* const* d_in, const int* in_sizes, int n_in,
                              void* d_out, int out_size, void* d_ws, size_t ws_size,
                              hipStream_t stream) {
  const float* x = (const float*)d_in[0];
  // d_in[1] = adj [8192*8192] int32 — dead code in reference, never read.
  const float* W = (const float*)d_in[2];
  const float* b = (const float*)d_in[3];
  // d_in[4] = a [8*128] f32 — dead code in reference, never read.
  float* out = (float*)d_out;

  unsigned short* xb = (unsigned short*)d_ws;            // 8192*512 bf16 = 8 MB
  unsigned short* wb = xb + (size_t)NROWS * KD;          // 512*512 bf16 = 0.5 MB
  // ws needed: 8.5 MB (re-generated every call; ws is poisoned between calls)

  cast_bf16_kernel<<<dim3(2176), dim3(256), 0, stream>>>(x, W, xb, wb);
  gemm_bias_gelu<<<dim3(4, 64), dim3(256), 0, stream>>>(xb, wb, b, out);
}

// Round 2
// 329.443 us; speedup vs baseline: 1.0157x; 1.0157x over previous
//
#include <hip/hip_runtime.h>
#include <math.h>

// out = GELU_exact(x @ W.T + b); x:[8192,512] f32, W:[512,512] f32, b:[512].
// adj (d_in[1]) and a (d_in[4]) are dead code in the reference.
//
// Round 2: single fused kernel. f32 loaded from global, cast to bf16 in
// registers (round-half-up + v_perm pack), staged to double-buffered LDS,
// 16x16x32 bf16 MFMA, fused bias + exact-GELU epilogue. No workspace use.
// Grid 512 blocks (2/CU) so one block's barrier drain hides behind the other.
// XCD swizzle: bm = id&127, bn = id>>7 -> the 4 bn-blocks sharing an x tile
// land on one XCD (ids differ by 128 = 0 mod 8) -> x fetched from HBM once.

#define KD   512
#define BM   64
#define BN   128
#define BK   32

using short8  = __attribute__((ext_vector_type(8))) short;
using floatx4 = __attribute__((ext_vector_type(4))) float;
using uintx4  = __attribute__((ext_vector_type(4))) unsigned int;

// pack two f32 -> two bf16 (round-half-up: +0x8000 then take high 16 bits).
// Unbiased nearest rounding for random data; 3 VALU ops per 2 elements.
__device__ __forceinline__ unsigned int pack2_bf16(float lo, float hi) {
  unsigned int ul = __float_as_uint(lo) + 0x8000u;
  unsigned int uh = __float_as_uint(hi) + 0x8000u;
  // dst = { uh[31:16], ul[31:16] } : v_perm_b32 (sel bytes: 0-3 from src1=ul)
  return __builtin_amdgcn_perm(uh, ul, 0x07060302u);
}

__device__ __forceinline__ uintx4 pack8_bf16(floatx4 v0, floatx4 v1) {
  uintx4 o;
  o[0] = pack2_bf16(v0[0], v0[1]);
  o[1] = pack2_bf16(v0[2], v0[3]);
  o[2] = pack2_bf16(v1[0], v1[1]);
  o[3] = pack2_bf16(v1[2], v1[3]);
  return o;
}

__global__ __launch_bounds__(256, 2) void fused_gemm_bias_gelu(
    const float* __restrict__ X,     // [8192][512]
    const float* __restrict__ W,     // [512][512] row = out-feature
    const float* __restrict__ bias,  // [512]
    float* __restrict__ C) {         // [8192][512]
  // double-buffered bf16 tiles: A 64x32, B 128x32 (m97 row layout, 64 B rows)
  __shared__ __align__(16) unsigned short lA[2][BM * BK];  // 2 x 4 KB
  __shared__ __align__(16) unsigned short lB[2][BN * BK];  // 2 x 8 KB

  const int tid  = threadIdx.x;
  const int id   = blockIdx.x;
  const int bm   = id & 127;   // 128 row-tiles of 64
  const int bn   = id >> 7;    // 4 col-tiles of 128
  const int wave = tid >> 6;
  const int lane = tid & 63;
  const int quad = lane >> 4;
  const int l16  = lane & 15;
  const int wm   = (wave >> 1) * 32;  // wave covers 32 rows x 64 cols
  const int wn   = (wave & 1) * 64;

  // staging maps: A 8 f32/thread, B 16 f32/thread
  const int rA = tid >> 2, eA = (tid & 3) * 8;   // A row 0..63, col-chunk
  const int rB = tid >> 1, eB = (tid & 1) * 16;  // B row 0..127

  const float* Ag = X + (size_t)(bm * BM + rA) * KD + eA;
  const float* Bg = W + (size_t)(bn * BN + rB) * KD + eB;

  floatx4 a0, a1, b0, b1, b2, b3;
#define ISSUE_LOADS(kt)                                  \
  do {                                                   \
    const float* pa = Ag + (kt) * BK;                    \
    a0 = *(const floatx4*)pa;                            \
    a1 = *(const floatx4*)(pa + 4);                      \
    const float* pb = Bg + (kt) * BK;                    \
    b0 = *(const floatx4*)pb;                            \
    b1 = *(const floatx4*)(pb + 4);                      \
    b2 = *(const floatx4*)(pb + 8);                      \
    b3 = *(const floatx4*)(pb + 12);                     \
  } while (0)

  ISSUE_LOADS(0);
  floatx4 acc[2][4] = {};

#pragma unroll
  for (int kt = 0; kt < KD / BK; ++kt) {
    const int buf = kt & 1;
    // cvt + stage current tile
    *(uintx4*)&lA[buf][rA * BK + eA]      = pack8_bf16(a0, a1);
    *(uintx4*)&lB[buf][rB * BK + eB]      = pack8_bf16(b0, b1);
    *(uintx4*)&lB[buf][rB * BK + eB + 8]  = pack8_bf16(b2, b3);
    if (kt < KD / BK - 1) ISSUE_LOADS(kt + 1);  // prefetch next K-step
    __syncthreads();
    // fragments: lane holds op[row=l16][k=quad*8..+7]
    short8 af[2], bfr[4];
#pragma unroll
    for (int i = 0; i < 2; ++i)
      af[i] = *(const short8*)&lA[buf][(wm + i * 16 + l16) * BK + quad * 8];
#pragma unroll
    for (int j = 0; j < 4; ++j)
      bfr[j] = *(const short8*)&lB[buf][(wn + j * 16 + l16) * BK + quad * 8];
#pragma unroll
    for (int i = 0; i < 2; ++i)
#pragma unroll
      for (int j = 0; j < 4; ++j)
        acc[i][j] = __builtin_amdgcn_mfma_f32_16x16x32_bf16(af[i], bfr[j],
                                                            acc[i][j], 0, 0, 0);
    // single barrier per iter: buf is safe to overwrite at kt+2 because
    // every wave's reads of buf precede barrier(kt+1) in program order.
  }
#undef ISSUE_LOADS

  // Epilogue: C/D layout col = lane&15, row = quad*4 + reg (verified R1).
  const int row0 = bm * BM + wm;
  const int col0 = bn * BN + wn;
  float bv[4];
#pragma unroll
  for (int j = 0; j < 4; ++j) bv[j] = bias[col0 + j * 16 + l16];
#pragma unroll
  for (int i = 0; i < 2; ++i) {
#pragma unroll
    for (int j = 0; j < 4; ++j) {
      const int col = col0 + j * 16 + l16;
#pragma unroll
      for (int r = 0; r < 4; ++r) {
        const int row = row0 + i * 16 + quad * 4 + r;
        float v = acc[i][j][r] + bv[j];
        float g = 0.5f * v * (1.0f + erff(v * 0.70710678118654752f));
        C[(size_t)row * KD + col] = g;
      }
    }
  }
}

extern "C" void kernel_launch(void* const* d_in, const int* in_sizes, int n_in,
                              void* d_out, int out_size, void* d_ws, size_t ws_size,
                              hipStream_t stream) {
  const float* x = (const float*)d_in[0];
  // d_in[1] = adj — dead code, never read.
  const float* W = (const float*)d_in[2];
  const float* b = (const float*)d_in[3];
  // d_in[4] = a — dead code, never read.
  float* out = (float*)d_out;
  fused_gemm_bias_gelu<<<dim3(512), dim3(256), 0, stream>>>(x, W, b, out);
}